// Round 1
// 465.094 us; speedup vs baseline: 1.0516x; 1.0516x over previous
//
#include <hip/hip_runtime.h>

// stepSSM v2: 4 lanes per row. Lane c of a row owns state chunk c (float4), which by the
// [h,f,re/im] layout is (hh = c>>1, f = 2*(c&1)+{0,1}). All states/out_states accesses are
// lane-stride-16B fully coalesced (1 KB contiguous per wave instruction) instead of the
// previous 64-B-stride pattern (4x line-transaction amplification). Cross-lane: 2 shfl_xor
// per layer. Streams marked non-temporal (zero reuse).

constexpr float NEG_SLOPE = 0.125f;

typedef float fv4 __attribute__((ext_vector_type(4)));

__global__ __launch_bounds__(256) void ssm_fused(
    const float* __restrict__ x,
    const float* __restrict__ states,
    const float* __restrict__ fc1_w,
    const float* __restrict__ fc1_b,
    const float* __restrict__ fc_w,
    const float* __restrict__ fc_b,
    const float* __restrict__ A,
    const float* __restrict__ Bm,
    const float* __restrict__ Cm,
    const float* __restrict__ Dm,
    float* __restrict__ out_h,
    float* __restrict__ out_states,
    int B)
{
    // LDS weight cache (same layout as v1), 16B-aligned so float4 chunks load as ds_read_b128.
    __shared__ __align__(16) float w[240];
    const int t = threadIdx.x;
    if (t < 240) {
        float v;
        if (t < 8)        v = fc1_w[t];
        else if (t < 10)  v = fc1_b[t - 8];
        else if (t < 30)  v = fc_w[t - 10];
        else if (t < 40)  v = fc_b[t - 30];
        else if (t < 104) v = A[t - 40];
        else if (t < 168) v = Bm[t - 104];
        else if (t < 232) v = Cm[t - 168];
        else              v = Dm[t - 232];
        w[t] = v;
    }
    __syncthreads();

    const int g = blockIdx.x * 256 + t;   // global lane id
    const int n = g >> 2;                 // row
    const int c = g & 3;                  // chunk: hh = c>>1, f = 2*(c&1)+{0,1}
    if (n >= B) return;

    // fc1: all 4 lanes of a row load the same float4 (same-line, coalesced broadcast)
    // and redundantly compute h0,h1 — keeps everything lane-local.
    const float4 xv = ((const float4*)x)[n];
    float h0 = w[8] + xv.x * w[0] + xv.y * w[1] + xv.z * w[2] + xv.w * w[3];
    float h1 = w[9] + xv.x * w[4] + xv.y * w[5] + xv.z * w[6] + xv.w * w[7];

    const float* wA  = w + 40;   // [4][2][4][2]
    const float* wB  = w + 104;
    const float* wC  = w + 168;
    const float* wD  = w + 232;  // [4][2]
    const float* wfc = w + 10;   // [5][2][2]
    const float* wfb = w + 30;   // [5][2]
    const bool hi = (c & 2) != 0;

#pragma unroll
    for (int i = 0; i < 4; ++i) {
        const size_t base = ((size_t)i * (size_t)B + (size_t)n) * 16 + (size_t)(c * 4);
        const fv4 s  = __builtin_nontemporal_load((const fv4*)(states + base));
        const fv4 a  = *(const fv4*)(wA + i * 16 + c * 4);  // (Ar0,Ai0,Ar1,Ai1)
        const fv4 b  = *(const fv4*)(wB + i * 16 + c * 4);
        const fv4 cc = *(const fv4*)(wC + i * 16 + c * 4);

        const float u = hi ? h1 : h0;
        const float nr0 = a.x * s.x - a.y * s.y + b.x * u;
        const float ni0 = a.x * s.y + a.y * s.x + b.y * u;
        const float nr1 = a.z * s.z - a.w * s.w + b.z * u;
        const float ni1 = a.z * s.w + a.w * s.z + b.w * u;

        // partial Re(C * ns) over this lane's two f's
        float part = cc.x * nr0 - cc.y * ni0 + cc.z * nr1 - cc.w * ni1;
        part += __shfl_xor(part, 1);               // sum over all 4 f within own hh
        const float other = __shfl_xor(part, 2);   // the other hh's sum
        const float acc0 = hi ? other : part;
        const float acc1 = hi ? part  : other;

        float y0 = 2.f * acc0 + h0 * wD[i * 2 + 0];
        float y1 = 2.f * acc1 + h1 * wD[i * 2 + 1];
        y0 = (y0 >= 0.f) ? y0 : NEG_SLOPE * y0;
        y1 = (y1 >= 0.f) ? y1 : NEG_SLOPE * y1;
        const float nh0 = wfb[i * 2 + 0] + wfc[i * 4 + 0] * y0 + wfc[i * 4 + 1] * y1;
        const float nh1 = wfb[i * 2 + 1] + wfc[i * 4 + 2] * y0 + wfc[i * 4 + 3] * y1;
        h0 = nh0; h1 = nh1;

        fv4 nsv; nsv.x = nr0; nsv.y = ni0; nsv.z = nr1; nsv.w = ni1;
        __builtin_nontemporal_store(nsv, (fv4*)(out_states + base));
    }

    // fc10 — one lane per row writes the 8B result.
    if (c == 0) {
        const float o0 = wfb[8] + wfc[16] * h0 + wfc[17] * h1;
        const float o1 = wfb[9] + wfc[18] * h0 + wfc[19] * h1;
        ((float2*)out_h)[n] = make_float2(o0, o1);
    }
}

extern "C" void kernel_launch(void* const* d_in, const int* in_sizes, int n_in,
                              void* d_out, int out_size, void* d_ws, size_t ws_size,
                              hipStream_t stream) {
    const float* x      = (const float*)d_in[0];
    const float* states = (const float*)d_in[1];
    const float* fc1_w  = (const float*)d_in[2];
    const float* fc1_b  = (const float*)d_in[3];
    const float* fc_w   = (const float*)d_in[4];
    const float* fc_b   = (const float*)d_in[5];
    const float* A      = (const float*)d_in[6];
    const float* Bm     = (const float*)d_in[7];
    const float* Cm     = (const float*)d_in[8];
    const float* Dm     = (const float*)d_in[9];
    const int B = in_sizes[0] / 4;   // same convention as the verified v1 kernel

    float* out_h      = (float*)d_out;
    float* out_states = (float*)d_out + (size_t)2 * (size_t)B;

    const long long threads = 4LL * (long long)B;  // 4 lanes per row
    dim3 grid((unsigned)((threads + 255) / 256)), block(256);
    hipLaunchKernelGGL(ssm_fused, grid, block, 0, stream,
                       x, states, fc1_w, fc1_b, fc_w, fc_b, A, Bm, Cm, Dm,
                       out_h, out_states, B);
}